// Round 2
// baseline (53.158 us; speedup 1.0000x reference)
//
#include <hip/hip_runtime.h>
#include <hip/hip_bf16.h>

// RotateChordVarLen: x [T, 256] f32, 16 tracks of 16 floats.
// out[t, track i] = x[start + (pos + shift_i) % len, track i],
// shift_0 = 0, shift_i = 2^(i-1).
//
// Mapping: one wave per token. lane l -> track l/4, float4 quad l%4.
// Writes perfectly coalesced (1 KiB/wave), streamed past L2 with nt stores
// (never re-read in-kernel). Reads are 16 x 64B contiguous chunks per wave;
// cached, so the 128B-line chunk pairs (read by tokens a few apart) hit L2.
// Segment search is scalarized (t is wave-uniform -> SALU + s_load).

typedef float f32x4 __attribute__((ext_vector_type(4)));

__global__ __launch_bounds__(256) void
rotate_chord_kernel(const float* __restrict__ x,
                    const int* __restrict__ lengths,
                    float* __restrict__ out,
                    int T, int B) {
    // token index — wave-uniform; force into SGPR so the segment loop is scalar
    int t = __builtin_amdgcn_readfirstlane(
        (int)((blockIdx.x * blockDim.x + threadIdx.x) >> 6));
    if (t >= T) return;
    int lane  = threadIdx.x & 63;
    int track = lane >> 2;         // 0..15
    int quad  = lane & 3;          // 0..3

    // Scalar segment search over B (=8) segments.
    int start = 0, len = 1, acc = 0;
    for (int b = 0; b < B; ++b) {
        int L = lengths[b];
        if (t >= acc) { start = acc; len = L; }
        acc += L;
    }
    unsigned pos  = (unsigned)(t - start);
    unsigned ulen = (unsigned)len;

    unsigned shift = (track == 0) ? 0u : (1u << (track - 1));
    unsigned sp = pos + shift;
    sp -= (sp / ulen) * ulen;      // (pos + shift) % len ; shift may exceed len
    int src = start + (int)sp;

    const f32x4* __restrict__ xr = reinterpret_cast<const f32x4*>(
        x + (size_t)src * 256 + track * 16 + quad * 4);
    f32x4 v = *xr;

    f32x4* __restrict__ wr = reinterpret_cast<f32x4*>(
        out + (size_t)t * 256 + (size_t)lane * 4);
    __builtin_nontemporal_store(v, wr);
}

extern "C" void kernel_launch(void* const* d_in, const int* in_sizes, int n_in,
                              void* d_out, int out_size, void* d_ws, size_t ws_size,
                              hipStream_t stream) {
    const float* x       = (const float*)d_in[0];
    const int*   lengths = (const int*)d_in[1];
    float*       out     = (float*)d_out;

    const int D = 256;
    int T = in_sizes[0] / D;
    int B = in_sizes[1];

    long long total_threads = (long long)T * 64;
    int blocks = (int)((total_threads + 255) / 256);

    rotate_chord_kernel<<<blocks, 256, 0, stream>>>(x, lengths, out, T, B);
}

// Round 3
// 49.901 us; speedup vs baseline: 1.0653x; 1.0653x over previous
//
#include <hip/hip_runtime.h>
#include <hip/hip_bf16.h>

// RotateChordVarLen: x [T, 256] f32, 16 tracks of 16 floats.
// out[t, track i] = x[start + (pos + shift_i) % len, track i],
// shift_0 = 0, shift_i = 2^(i-1).
//
// Mapping: one wave per token-pair (t0, t0+4); block of 4 waves covers 8
// consecutive tokens. lane l -> track l/4, float4 quad l%4.
// Writes: plain (L2-routed) coalesced 1 KiB/wave stores — nt stores measured
// -10% in R2, reverted. Reads: 16 x 64B contiguous chunks per wave, cached so
// the 128B-line track-pair reuse (tokens Delta apart) hits L1/L2/L3.
// Two independent loads per lane for ILP / outstanding-VMEM depth.

typedef float f32x4 __attribute__((ext_vector_type(4)));

__global__ __launch_bounds__(256) void
rotate_chord_kernel(const float* __restrict__ x,
                    const int* __restrict__ lengths,
                    float* __restrict__ out,
                    int T, int B) {
    int wave  = threadIdx.x >> 6;        // 0..3
    int lane  = threadIdx.x & 63;
    int track = lane >> 2;               // 0..15
    int quad  = lane & 3;                // 0..3
    int t0    = blockIdx.x * 8 + wave;   // this wave's tokens: t0, t0+4
    if (t0 >= T) return;

    unsigned shift = (track == 0) ? 0u : (1u << (track - 1));
    int col = track * 16 + quad * 4;

    size_t srcoff[2];
#pragma unroll
    for (int k = 0; k < 2; ++k) {
        int t = t0 + 4 * k;
        // Per-lane segment search over B (=8) segments — cheap VALU.
        int start = 0, len = 1, acc = 0;
        for (int b = 0; b < B; ++b) {
            int L = lengths[b];
            if (t >= acc) { start = acc; len = L; }
            acc += L;
        }
        unsigned sp = (unsigned)(t - start) + shift;
        sp -= (sp / (unsigned)len) * (unsigned)len;   // (pos+shift) % len
        srcoff[k] = (size_t)(start + (int)sp) * 256 + col;
    }

    bool has2 = (t0 + 4) < T;
    f32x4 v0 = *reinterpret_cast<const f32x4*>(x + srcoff[0]);
    f32x4 v1 = has2 ? *reinterpret_cast<const f32x4*>(x + srcoff[1]) : v0;

    *reinterpret_cast<f32x4*>(out + (size_t)t0 * 256 + lane * 4) = v0;
    if (has2)
        *reinterpret_cast<f32x4*>(out + (size_t)(t0 + 4) * 256 + lane * 4) = v1;
}

extern "C" void kernel_launch(void* const* d_in, const int* in_sizes, int n_in,
                              void* d_out, int out_size, void* d_ws, size_t ws_size,
                              hipStream_t stream) {
    const float* x       = (const float*)d_in[0];
    const int*   lengths = (const int*)d_in[1];
    float*       out     = (float*)d_out;

    const int D = 256;
    int T = in_sizes[0] / D;
    int B = in_sizes[1];

    // 8 tokens per block of 256 threads.
    int blocks = (T + 7) / 8;

    rotate_chord_kernel<<<blocks, 256, 0, stream>>>(x, lengths, out, T, B);
}